// Round 6
// baseline (562.895 us; speedup 1.0000x reference)
//
#include <hip/hip_runtime.h>

// MoE expert FFN: T=256, E=16, H=2048, I=1024, top_k=4 (int32 device scalar).
// Inputs fp32, output fp32 (both proven). Compute bf16 MFMA (threshold 2%).
//
// R8: SPLIT STREAM FROM COMPUTE. Evidence R0-R5: every gemm structure
// streams fp32 weights at ~1.5-2 TB/s, while pure streams (harness fill,
// m13 copy) hit 6.3-6.7 TB/s on this chip. So:
//   wconv: w1,w2 fp32 -> bf16 into ws (384 MB read + 192 MB write, pure
//          high-occupancy stream, ~92us at stream rate). The 192 MB of
//          bf16 weights fit in the 256 MB L3 -> gemm weight reads become
//          L2/L3 hits (~200cy) instead of congested HBM misses (~900cy+).
//   gemms: EXACT R4 structure (best so far, 504us) with bf16 B-loads:
//          half the staged bytes, zero f2bf VALU in the k-loop.
// Everything else (route/convert_x/gather, MFMA C/D mapping, silu fusion,
// LDS dbuf + issue-early/write-late, LDW=72 pad) unchanged from R4.

typedef __attribute__((ext_vector_type(8))) short bf16x8;   // MFMA A/B frag
typedef __attribute__((ext_vector_type(4))) float floatx4;  // MFMA C/D frag

#define T_TOK 256
#define N_EXP 16
#define H_DIM 2048
#define I_DIM 1024
#define MAX_SLOTS 256
#define BK 64
#define LDW 72                    // padded LDS row stride (shorts); 144B
#define TILE (128 * LDW)          // shorts per tile buffer
#define NT1 (H_DIM / BK)          // 32 K-steps (gemm1)
#define NT2 (I_DIM / BK)          // 16 K-steps (gemm2)

__device__ __forceinline__ short f2bf(float f) {           // RNE fp32->bf16
    union { float f; unsigned u; } v; v.f = f;
    unsigned r = (v.u + 0x7FFFu + ((v.u >> 16) & 1u)) >> 16;
    return (short)r;
}
__device__ __forceinline__ float bf2f(short s) {
    union { unsigned u; float f; } v; v.u = ((unsigned)(unsigned short)s) << 16;
    return v.f;
}
__device__ __forceinline__ bf16x8 pack2f4(float4 a, float4 b) {  // 8 fp32 -> bf16x8
    bf16x8 r;
    r[0] = f2bf(a.x); r[1] = f2bf(a.y); r[2] = f2bf(a.z); r[3] = f2bf(a.w);
    r[4] = f2bf(b.x); r[5] = f2bf(b.y); r[6] = f2bf(b.z); r[7] = f2bf(b.w);
    return r;
}
__device__ __forceinline__ bf16x8 pack8(const float* __restrict__ p) {
    return pack2f4(*(const float4*)p, *(const float4*)(p + 4));
}

// ---------------- weight fp32 -> bf16 (pure stream; m13-style) ----------------
// one thread = 16 floats (64B read, 32B write). grid covers n exactly.
__global__ __launch_bounds__(256) void wconv_kernel(
    const float* __restrict__ src, short* __restrict__ dst)
{
    const size_t i = ((size_t)blockIdx.x * 256 + threadIdx.x) * 16;
    float4 a0 = *(const float4*)(src + i),     a1 = *(const float4*)(src + i + 4);
    float4 b0 = *(const float4*)(src + i + 8), b1 = *(const float4*)(src + i + 12);
    *(bf16x8*)(dst + i)     = pack2f4(a0, a1);
    *(bf16x8*)(dst + i + 8) = pack2f4(b0, b1);
}

// ---------------- x fp32 -> bf16 ----------------
__global__ __launch_bounds__(256) void convert_x_kernel(
    const float* __restrict__ xf, short* __restrict__ xb)
{
    const int i = (blockIdx.x * 256 + threadIdx.x) * 8;
    *(bf16x8*)(xb + i) = pack8(xf + i);
}

// ---------------- routing ----------------
__global__ __launch_bounds__(256) void route_kernel(
    const float* __restrict__ logits,   // [256][16] fp32
    const int* __restrict__ topk_ptr,
    int* __restrict__ counts, int* __restrict__ tokens,
    int* __restrict__ tok_e, int* __restrict__ tok_slot, float* __restrict__ tok_wt)
{
    __shared__ int lds_counts[N_EXP];
    const int t = threadIdx.x;
    if (t < N_EXP) lds_counts[t] = 0;
    __syncthreads();

    int K = topk_ptr[0];
    if (K > 8) K = 8;
    if (K < 1) K = 1;

    float l[N_EXP];
    #pragma unroll
    for (int j = 0; j < N_EXP; ++j) l[j] = logits[t * N_EXP + j];

    float M = l[0];
    #pragma unroll
    for (int j = 1; j < N_EXP; ++j) M = fmaxf(M, l[j]);

    // top-K by logit; strict > keeps lowest index on ties (matches lax.top_k)
    int idx[8]; float lv[8]; unsigned used = 0u;
    for (int k = 0; k < K; ++k) {
        int bi = 0; float bv = -1e30f;
        #pragma unroll
        for (int j = 0; j < N_EXP; ++j)
            if (!((used >> j) & 1u) && l[j] > bv) { bv = l[j]; bi = j; }
        used |= 1u << bi;
        idx[k] = bi; lv[k] = bv;
    }
    float w[8], s = 0.f;
    for (int k = 0; k < K; ++k) { w[k] = __expf(lv[k] - M); s += w[k]; }
    const float inv = 1.0f / s;

    for (int k = 0; k < K; ++k) {
        const int e = idx[k];
        const int slot = atomicAdd(&lds_counts[e], 1);
        tokens[e * MAX_SLOTS + slot] = t;
        tok_e[t * 8 + k] = e; tok_slot[t * 8 + k] = slot; tok_wt[t * 8 + k] = w[k] * inv;
    }
    __syncthreads();
    if (t < N_EXP) counts[t] = lds_counts[t];
}

// ---------------- GEMM1: act = silu(X_e @ Wg^T) * (X_e @ Wu^T) ----------------
// grid (16 experts, 16 i-blocks of 64). 512 threads = 8 waves.
// B-tile = 128 w1b rows (64 gate + 64 up). Wave: gu=wave>>2, iw=wave&3.
// A-tile = 128 token rows (clamped). Double-buffered LDS, issue-early /
// write-late (R4-proven). Weights are bf16 (wconv) -> 2 loads/thread/K-step.
__global__ __launch_bounds__(512, 2) void gemm1_kernel(
    const short* __restrict__ xb,     // [256][2048] bf16
    const short* __restrict__ w1b,    // [16][2048][2048] bf16
    const int* __restrict__ counts, const int* __restrict__ tokens,
    short* __restrict__ act)          // [16][256][1024] bf16
{
    __shared__ short lds[4 * TILE];   // A0 A1 B0 B1 = 72 KB
    const int e = blockIdx.x;
    const int count = counts[e];
    if (count == 0) return;
    const int tid = (int)threadIdx.x;
    const int wave = tid >> 6, lane = tid & 63;
    const int gu = wave >> 2, iw = wave & 3;
    const int nl = lane & 15, quad = lane >> 4;
    const int i_base = blockIdx.y * 64;
    const int* toks = tokens + e * MAX_SLOTS;

    // staging coords: thread t covers tile row sr = t/4, 16 elems at col sk
    const int sr = tid >> 2;
    const int sk = (tid & 3) << 4;
    const int w1row = i_base + (sr & 63) + ((sr >> 6) << 10);   // gate | up
    const short* wsrc = w1b + ((size_t)e * H_DIM + w1row) * H_DIM + sk;
    const int st = sr * LDW + sk;     // LDS offset (shorts)

    for (int ms = 0; ms < count; ms += 128) {
        int slotS = ms + sr; if (slotS >= count) slotS = count - 1;  // clamp
        const short* asrc = xb + (size_t)toks[slotS] * H_DIM + sk;

        floatx4 acc[8];
        #pragma unroll
        for (int mt = 0; mt < 8; ++mt) acc[mt] = (floatx4)0.0f;

        // prologue: stage kt=0 into buffers 0
        {
            bf16x8 b0 = *(const bf16x8*)(wsrc + 0), b1 = *(const bf16x8*)(wsrc + 8);
            bf16x8 a0 = *(const bf16x8*)(asrc + 0), a1 = *(const bf16x8*)(asrc + 8);
            *(bf16x8*)(lds + 0 * TILE + st) = a0;
            *(bf16x8*)(lds + 0 * TILE + st + 8) = a1;
            *(bf16x8*)(lds + 2 * TILE + st) = b0;
            *(bf16x8*)(lds + 2 * TILE + st + 8) = b1;
        }
        __syncthreads();

        for (int kt = 0; kt < NT1; ++kt) {
            const int cur = kt & 1, nxt = cur ^ 1;
            const bool pf = (kt + 1 < NT1);
            bf16x8 b0, b1, a0, a1;
            if (pf) {                                  // issue-early (T14)
                const short* ws = wsrc + (kt + 1) * BK;
                const short* as = asrc + (kt + 1) * BK;
                b0 = *(const bf16x8*)(ws + 0);  b1 = *(const bf16x8*)(ws + 8);
                a0 = *(const bf16x8*)(as + 0);  a1 = *(const bf16x8*)(as + 8);
            }
            const short* A = lds + cur * TILE;
            const short* B = lds + (2 + cur) * TILE;
            #pragma unroll
            for (int c = 0; c < 2; ++c) {
                bf16x8 bf = *(const bf16x8*)(B + (gu * 64 + iw * 16 + nl) * LDW + c * 32 + quad * 8);
                #pragma unroll
                for (int mt = 0; mt < 8; ++mt) {
                    bf16x8 af = *(const bf16x8*)(A + (mt * 16 + nl) * LDW + c * 32 + quad * 8);
                    acc[mt] = __builtin_amdgcn_mfma_f32_16x16x32_bf16(af, bf, acc[mt], 0, 0, 0);
                }
            }
            if (pf) {                                  // write-late
                *(bf16x8*)(lds + nxt * TILE + st) = a0;
                *(bf16x8*)(lds + nxt * TILE + st + 8) = a1;
                *(bf16x8*)(lds + (2 + nxt) * TILE + st) = b0;
                *(bf16x8*)(lds + (2 + nxt) * TILE + st + 8) = b1;
            }
            __syncthreads();
        }

        // epilogue: up waves publish acc via LDS; gate waves silu+store.
        floatx4* epi = (floatx4*)lds;   // 32 KB alias (safe after barrier)
        if (gu == 1) {
            #pragma unroll
            for (int mt = 0; mt < 8; ++mt) epi[(iw * 8 + mt) * 64 + lane] = acc[mt];
        }
        __syncthreads();
        if (gu == 0) {
            #pragma unroll
            for (int mt = 0; mt < 8; ++mt) {
                floatx4 u = epi[(iw * 8 + mt) * 64 + lane];
                #pragma unroll
                for (int r = 0; r < 4; ++r) {
                    const int slot = ms + mt * 16 + quad * 4 + r;   // D: row=quad*4+r, col=nl
                    if (slot < count) {
                        const float g = acc[mt][r], uv = u[r];
                        const float a = g / (1.0f + __expf(-g)) * uv;   // silu(g)*u
                        act[(size_t)(e * MAX_SLOTS + slot) * I_DIM + i_base + iw * 16 + nl] = f2bf(a);
                    }
                }
            }
        }
        __syncthreads();   // lds reused by next ms pass
    }
}

// ---------------- GEMM2: y = act_e @ w2[e]^T ----------------
// grid (16 experts, 16 h-blocks of 128). 512 threads = 8 waves; wave owns
// h-rows wave*16+nl. Same burst-staged double-buffer structure; no reduce.
__global__ __launch_bounds__(512, 2) void gemm2_kernel(
    const short* __restrict__ act,    // [16][256][1024] bf16
    const short* __restrict__ w2b,    // [16][2048][1024] bf16
    const int* __restrict__ counts,
    short* __restrict__ y)            // [16][256][2048] bf16
{
    __shared__ short lds[4 * TILE];
    const int e = blockIdx.x;
    const int count = counts[e];
    if (count == 0) return;
    const int tid = (int)threadIdx.x;
    const int wave = tid >> 6, lane = tid & 63;
    const int nl = lane & 15, quad = lane >> 4;
    const int h_base = blockIdx.y * 128;

    const int sr = tid >> 2;
    const int sk = (tid & 3) << 4;
    const short* wsrc = w2b + ((size_t)e * H_DIM + h_base + sr) * I_DIM + sk;
    const short* acte = act + (size_t)e * MAX_SLOTS * I_DIM;
    const int st = sr * LDW + sk;

    for (int ms = 0; ms < count; ms += 128) {
        int slotS = ms + sr; if (slotS >= count) slotS = count - 1;
        const short* asrc = acte + (size_t)slotS * I_DIM + sk;

        floatx4 acc[8];
        #pragma unroll
        for (int mt = 0; mt < 8; ++mt) acc[mt] = (floatx4)0.0f;

        {
            bf16x8 b0 = *(const bf16x8*)(wsrc + 0), b1 = *(const bf16x8*)(wsrc + 8);
            bf16x8 a0 = *(const bf16x8*)(asrc + 0), a1 = *(const bf16x8*)(asrc + 8);
            *(bf16x8*)(lds + 0 * TILE + st) = a0;
            *(bf16x8*)(lds + 0 * TILE + st + 8) = a1;
            *(bf16x8*)(lds + 2 * TILE + st) = b0;
            *(bf16x8*)(lds + 2 * TILE + st + 8) = b1;
        }
        __syncthreads();

        for (int kt = 0; kt < NT2; ++kt) {
            const int cur = kt & 1, nxt = cur ^ 1;
            const bool pf = (kt + 1 < NT2);
            bf16x8 b0, b1, a0, a1;
            if (pf) {
                const short* ws = wsrc + (kt + 1) * BK;
                const short* as = asrc + (kt + 1) * BK;
                b0 = *(const bf16x8*)(ws + 0);  b1 = *(const bf16x8*)(ws + 8);
                a0 = *(const bf16x8*)(as + 0);  a1 = *(const bf16x8*)(as + 8);
            }
            const short* A = lds + cur * TILE;
            const short* B = lds + (2 + cur) * TILE;
            #pragma unroll
            for (int c = 0; c < 2; ++c) {
                bf16x8 bf = *(const bf16x8*)(B + (wave * 16 + nl) * LDW + c * 32 + quad * 8);
                #pragma unroll
                for (int mt = 0; mt < 8; ++mt) {
                    bf16x8 af = *(const bf16x8*)(A + (mt * 16 + nl) * LDW + c * 32 + quad * 8);
                    acc[mt] = __builtin_amdgcn_mfma_f32_16x16x32_bf16(af, bf, acc[mt], 0, 0, 0);
                }
            }
            if (pf) {
                *(bf16x8*)(lds + nxt * TILE + st) = a0;
                *(bf16x8*)(lds + nxt * TILE + st + 8) = a1;
                *(bf16x8*)(lds + (2 + nxt) * TILE + st) = b0;
                *(bf16x8*)(lds + (2 + nxt) * TILE + st + 8) = b1;
            }
            __syncthreads();
        }

        #pragma unroll
        for (int mt = 0; mt < 8; ++mt) {
            #pragma unroll
            for (int r = 0; r < 4; ++r) {
                const int slot = ms + mt * 16 + quad * 4 + r;
                if (slot < count)
                    y[(size_t)(e * MAX_SLOTS + slot) * H_DIM + h_base + wave * 16 + nl] = f2bf(acc[mt][r]);
            }
        }
        __syncthreads();   // lds reused by next ms pass
    }
}

// ---------------- gather: out[t][h] = sum_k wt * y[e_k][slot_k][h] (fp32) ----------------
__global__ __launch_bounds__(256) void gather_kernel(
    const short* __restrict__ y, const int* __restrict__ topk_ptr,
    const int* __restrict__ tok_e, const int* __restrict__ tok_slot,
    const float* __restrict__ tok_wt, float* __restrict__ out)
{
    const int t = blockIdx.x;
    int K = topk_ptr[0];
    if (K > 8) K = 8;
    if (K < 1) K = 1;
    int e[8], sl[8]; float w[8];
    for (int k = 0; k < K; ++k) {
        e[k] = tok_e[t * 8 + k]; sl[k] = tok_slot[t * 8 + k]; w[k] = tok_wt[t * 8 + k];
    }
    for (int h = threadIdx.x; h < H_DIM; h += 256) {
        float s = 0.f;
        for (int k = 0; k < K; ++k)
            s += w[k] * bf2f(y[(size_t)(e[k] * MAX_SLOTS + sl[k]) * H_DIM + h]);
        out[(size_t)t * H_DIM + h] = s;
    }
}

// ---------------- launch ----------------
extern "C" void kernel_launch(void* const* d_in, const int* in_sizes, int n_in,
                              void* d_out, int out_size, void* d_ws, size_t ws_size,
                              hipStream_t stream)
{
    const float* x  = (const float*)d_in[0];
    const float* rl = (const float*)d_in[1];
    const float* w1 = (const float*)d_in[2];
    const float* w2 = (const float*)d_in[3];
    const int* topk = (const int*)d_in[4];

    char* ws = (char*)d_ws;
    int*   counts   = (int*)  (ws + 0);          //   64 B
    int*   tokens   = (int*)  (ws + 256);        //  16 KB [16][256]
    int*   tok_e    = (int*)  (ws + 16640);      //   8 KB [256][8]
    int*   tok_slot = (int*)  (ws + 24832);      //   8 KB
    float* tok_wt   = (float*)(ws + 33024);      //   8 KB
    short* xb       = (short*)(ws + 65536);      //   1 MB [256][2048] bf16
    short* act      = (short*)(ws + 1114112);    //   8 MB [16][256][1024] bf16
    short* yb       = (short*)(ws + 9502720);    //  16 MB [16][256][2048] bf16
    short* w1b      = (short*)(ws + 67108864);   // 128 MB [16][2048][2048] bf16
    short* w2b      = (short*)(ws + 201326592);  //  64 MB [16][2048][1024] bf16

    convert_x_kernel<<<256, 256, 0, stream>>>(x, xb);
    route_kernel<<<1, 256, 0, stream>>>(rl, topk, counts, tokens, tok_e, tok_slot, tok_wt);
    // w2 first, w1 second: w1b is the hotter-in-L3 one when gemm1 launches.
    wconv_kernel<<<(N_EXP * H_DIM * I_DIM) / (256 * 16), 256, 0, stream>>>(w2, w2b);
    wconv_kernel<<<(N_EXP * H_DIM * H_DIM) / (256 * 16), 256, 0, stream>>>(w1, w1b);
    gemm1_kernel<<<dim3(N_EXP, 16), 512, 0, stream>>>(xb, w1b, counts, tokens, act);
    gemm2_kernel<<<dim3(N_EXP, 16), 512, 0, stream>>>(act, w2b, counts, yb);
    gather_kernel<<<T_TOK, 256, 0, stream>>>(yb, topk, tok_e, tok_slot, tok_wt, (float*)d_out);
}